// Round 11
// baseline (417.612 us; speedup 1.0000x reference)
//
#include <hip/hip_runtime.h>
#include <hip/hip_bf16.h>

// Problem constants
#define TT   20
#define TS   19          // T-1 steps
#define BB   16
#define HH   128
#define WW   128
#define CHN  64
#define NOUT 10
#define BETA 0.9f
#define THRV 1.0f

#define RSTRIDE  24      // dwords per staged row (18 used + 6 pad; <=2-way bank aliasing)
#define PLSTRIDE 120     // dwords per plane: 5 rows (rows 0-3 data, row 4 zero dummy)
#define WVSTRIDE 240     // dwords per wave region (2 planes)

#define NBLK    2048     // lif grid blocks (2 x 64 x 16)
#define NSLOT   (NBLK*4) // wave slots
#define PDWORDS (NSLOT*TS*16)   // 2,490,368 dwords = 9.96 MB partial-count buffer

typedef __attribute__((ext_vector_type(8))) short short8;
typedef __attribute__((ext_vector_type(4))) float float4v;
typedef __attribute__((ext_vector_type(4))) int   int4v;

// round-to-nearest-even fp32 -> bf16 bits
__device__ __forceinline__ unsigned rne16(float f) {
    unsigned u = __float_as_uint(f);
    return (u + 0x7fffu + ((u >> 16) & 1u)) >> 16;
}
__device__ __forceinline__ float b2f(unsigned us) {
    return __uint_as_float(us << 16);
}

// ---------------------------------------------------------------------------
// Fused flow-diff + 3x3 conv (bf16-split MFMA) + LIF scan + spike count.
//
// ATOMIC-FREE hot loop (R10 found WRITE_SIZE 38.9MB: device-scope atomics to
// the shared spikesum bounce to LLC/HBM ~600-900cyc and sit in the vmcnt
// FIFO ahead of every prefetch-load wait). Instead each wave stores its
// packed per-t counts (16 dwords, plain global_store to a wave-private ws
// region) issued AFTER the prefetch loads -> always younger than any load
// being waited on -> never drained on the critical path. head_kernel sums
// the 512 wave-partials per (t,b).
//
// BRANCH-FREE A-fragments: bias rides tap k=30 (A dword3 low half = 1.0 for
// ALL lanes; for q<3 it multiplies B=0 -> harmless; q==3 B holds bias split).
// q==3 lanes read staged row 3 (x B=0) and zeroed dummy row 4 - uniform
// straight-line ds_reads, no exec-mask juggling (was lane-divergent in R10).
//
// Wave-private LDS staging (no __syncthreads; DS pipe is in-order per wave,
// asm memory fences only). x register-carried (rb=ra rotation, one float2
// load/slot/t). C-init fresh zero per t (R8: in-place C chains kill overlap).
// u = Ah*Bh + Al*Bh + Ah*Bl. A: m=lane&15, k=quad*8+j. C/D: row=q*4+reg,
// col=lane&15.
// ---------------------------------------------------------------------------
__global__ __launch_bounds__(256, 6) void lif_main(const float* __restrict__ x,
                                                   const float* __restrict__ w_conv,
                                                   const float* __restrict__ b_conv,
                                                   unsigned* __restrict__ P) {
    __shared__ unsigned lds[4 * WVSTRIDE];       // 3840 B

    const float2* xp2 = (const float2*)x;        // pixel-granular (ci pair)
    const int FRAME2  = BB * HH * WW;            // float2s per time slice

    const int tid  = threadIdx.x;
    const int lane = tid & 63;
    const int wv   = __builtin_amdgcn_readfirstlane(tid >> 6); // uniform 0..3
    const int bx   = blockIdx.x;                 // 0..1 : pixel half
    const int r0   = blockIdx.y << 1;            // first of 2 output rows
    const int bz   = blockIdx.z;                 // batch
    const int q    = lane >> 4;                  // quad
    const int col  = lane & 15;
    const int x0w  = (bx << 6) + (wv << 4);      // wave's 16-px base

    // ---- zero dummy row 4 of both planes (read by q==3, x B=0; avoid NaN)
    if (lane < 48) {
        int pl = lane / 24, i = lane - pl * 24;
        lds[wv * WVSTRIDE + pl * PLSTRIDE + 4 * RSTRIDE + i] = 0u;
    }

    // ---- t-invariant wave-private staging slots (slot = one pixel pair)
    const int  s0r = lane / 18, s0i = lane - s0r * 18;
    const int  y0s = r0 - 1 + s0r;
    const int  p0s = x0w - 1 + s0i;
    const bool v0  = ((unsigned)y0s < (unsigned)HH) && ((unsigned)p0s < (unsigned)WW);
    const int  g0  = v0 ? (y0s * WW + p0s) : 0;
    const int  a0  = wv * WVSTRIDE + s0r * RSTRIDE + s0i;

    const bool act1 = (lane < 8);                // slots 64..71 = (r=3, i=10..17)
    const int  y1s = r0 + 2;
    const int  p1s = x0w + 9 + lane;
    const bool v1  = act1 && ((unsigned)y1s < (unsigned)HH) && ((unsigned)p1s < (unsigned)WW);
    const int  g1  = v1 ? (y1s * WW + p1s) : 0;
    const int  a1  = wv * WVSTRIDE + 3 * RSTRIDE + 10 + lane;

    // ---- B fragments: k = q*8+j ; q<3,j<6: weights ; q==3,j==6 (k=30): bias
    short8 Bh[4], Bl[4];
#pragma unroll
    for (int cg = 0; cg < 4; ++cg) {
        int hi_i[4] = {0, 0, 0, 0}, lo_i[4] = {0, 0, 0, 0};
        if (q < 3) {
#pragma unroll
            for (int j = 0; j < 6; ++j) {
                float w = w_conv[((q * 3 + (j >> 1)) * 2 + (j & 1)) * CHN + cg * 16 + col];
                unsigned hs = rne16(w);
                unsigned ls = rne16(w - b2f(hs));
                hi_i[j >> 1] |= (int)(hs << (16 * (j & 1)));
                lo_i[j >> 1] |= (int)(ls << (16 * (j & 1)));
            }
        } else {
            float bb = b_conv[cg * 16 + col];
            unsigned hs = rne16(bb);
            unsigned ls = rne16(bb - b2f(hs));
            hi_i[3] = (int)hs;                   // k=30, low half
            lo_i[3] = (int)ls;
        }
        int4v hv = {hi_i[0], hi_i[1], hi_i[2], hi_i[3]};
        int4v lv = {lo_i[0], lo_i[1], lo_i[2], lo_i[3]};
        Bh[cg] = __builtin_bit_cast(short8, hv);
        Bl[cg] = __builtin_bit_cast(short8, lv);
    }

    float V0[4][4], V1[4][4];                    // membrane, rows r0, r0+1
#pragma unroll
    for (int cg = 0; cg < 4; ++cg)
#pragma unroll
        for (int r = 0; r < 4; ++r) { V0[cg][r] = 0.f; V1[cg][r] = 0.f; }

    // ---- A-read bases (t-invariant; q==3 reads rows 3 and 4-dummy)
    const unsigned* hp = lds + wv * WVSTRIDE + q * RSTRIDE + col;
    const unsigned* lp = hp + PLSTRIDE;

    // ---- partial-count store base: slot = blockLinear*4 + wv
    const int blkLin = bx + 2 * ((int)blockIdx.y + 64 * bz);
    int pidx = ((blkLin * 4 + wv) * TS) * 16 + col;

    // ---- preheader: rb = x[0], ra = x[1] (invalid slots stay 0 forever)
    float2 rb0 = {0.f, 0.f}, ra0 = {0.f, 0.f};
    float2 rb1 = {0.f, 0.f}, ra1 = {0.f, 0.f};
    {
        const int sA = bz * (HH * WW);
        const int sB = (BB + bz) * (HH * WW);
        if (v0) { rb0 = xp2[sA + g0]; ra0 = xp2[sB + g0]; }
        if (v1) { rb1 = xp2[sA + g1]; ra1 = xp2[sB + g1]; }
    }
    const float2* nx = xp2 + (size_t)(2 * BB + bz) * (HH * WW);  // slice t+2

    __asm volatile("" ::: "memory");

    for (int t = 0; t < TS; ++t) {
        // ---- pack flow = ra - rb into wave-private hi/lo planes
        {
            float d0 = ra0.x - rb0.x, d1 = ra0.y - rb0.y;
            unsigned ph0 = rne16(d0), ph1 = rne16(d1);
            unsigned pl0 = rne16(d0 - b2f(ph0)), pl1 = rne16(d1 - b2f(ph1));
            lds[a0]            = ph0 | (ph1 << 16);
            lds[a0 + PLSTRIDE] = pl0 | (pl1 << 16);
        }
        if (act1) {
            float d0 = ra1.x - rb1.x, d1 = ra1.y - rb1.y;
            unsigned ph0 = rne16(d0), ph1 = rne16(d1);
            unsigned pl0 = rne16(d0 - b2f(ph0)), pl1 = rne16(d1 - b2f(ph1));
            lds[a1]            = ph0 | (ph1 << 16);
            lds[a1 + PLSTRIDE] = pl0 | (pl1 << 16);
        }
        __asm volatile("" ::: "memory");         // keep reads below writes

        // ---- rotate + issue loads for next t (slice t+2)
        if (t < TS - 1) {
            rb0 = ra0; rb1 = ra1;
            if (v0) ra0 = nx[g0];
            if (v1) ra1 = nx[g1];
            nx += FRAME2;
        }

        // ---- A fragments: uniform, unconditional (12 dwords)
        unsigned h0 = hp[0], h1 = hp[1], h2 = hp[2];
        unsigned h3 = hp[RSTRIDE], h4 = hp[RSTRIDE + 1], h5 = hp[RSTRIDE + 2];
        unsigned l0 = lp[0], l1 = lp[1], l2 = lp[2];
        unsigned l3 = lp[RSTRIDE], l4 = lp[RSTRIDE + 1], l5 = lp[RSTRIDE + 2];
        __asm volatile("" ::: "memory");         // keep next writes below reads

        // dword3 low half = bf16 1.0 (k=30 bias tap; x B=0 for q<3)
        int4v a0h = {(int)h0, (int)h1, (int)h2, 0x00003f80};
        int4v a0l = {(int)l0, (int)l1, (int)l2, 0};
        int4v a1h = {(int)h3, (int)h4, (int)h5, 0x00003f80};
        int4v a1l = {(int)l3, (int)l4, (int)l5, 0};
        short8 A0h = __builtin_bit_cast(short8, a0h);
        short8 A0l = __builtin_bit_cast(short8, a0l);
        short8 A1h = __builtin_bit_cast(short8, a1h);
        short8 A1l = __builtin_bit_cast(short8, a1l);

        // ---- conv (MFMA) + LIF + byte-packed counts
        unsigned cpk = 0;
#pragma unroll
        for (int cg = 0; cg < 4; ++cg) {
            float4v u0 = {0.f, 0.f, 0.f, 0.f};
            float4v u1 = {0.f, 0.f, 0.f, 0.f};
            u0 = __builtin_amdgcn_mfma_f32_16x16x32_bf16(A0h, Bh[cg], u0, 0, 0, 0);
            u1 = __builtin_amdgcn_mfma_f32_16x16x32_bf16(A1h, Bh[cg], u1, 0, 0, 0);
            u0 = __builtin_amdgcn_mfma_f32_16x16x32_bf16(A0l, Bh[cg], u0, 0, 0, 0);
            u1 = __builtin_amdgcn_mfma_f32_16x16x32_bf16(A1l, Bh[cg], u1, 0, 0, 0);
            u0 = __builtin_amdgcn_mfma_f32_16x16x32_bf16(A0h, Bl[cg], u0, 0, 0, 0);
            u1 = __builtin_amdgcn_mfma_f32_16x16x32_bf16(A1h, Bl[cg], u1, 0, 0, 0);
            int c = 0;
#pragma unroll
            for (int r = 0; r < 4; ++r) {
                float vv0 = fmaf(BETA, V0[cg][r], u0[r]);
                bool  sp0 = vv0 > THRV;
                c += sp0 ? 1 : 0;
                V0[cg][r] = sp0 ? (vv0 - THRV) : vv0;
                float vv1 = fmaf(BETA, V1[cg][r], u1[r]);
                bool  sp1 = vv1 > THRV;
                c += sp1 ? 1 : 0;
                V1[cg][r] = sp1 ? (vv1 - THRV) : vv1;
            }
            cpk |= (unsigned)c << (8 * cg);
        }
        cpk += __shfl_xor(cpk, 16);              // reduce over quads
        cpk += __shfl_xor(cpk, 32);              // byte cg = ch cg*16+col
        // plain store, wave-private line, issued AFTER this iter's loads ->
        // never drained by the next load-wait (FIFO). Lanes 0..15 cover cols.
        if (lane < 16) P[pidx] = cpk;
        pidx += 16;
    }
}

// ---------------------------------------------------------------------------
// head: grid (TS, BB) x 256. Sums the 512 wave-partials for (t,b), computes
// logits[t][b][:], stashes per-(t,b) total spikes for final_kernel.
// ---------------------------------------------------------------------------
__global__ __launch_bounds__(256) void head_kernel(const unsigned* __restrict__ P,
                                                   const float* __restrict__ w_head,
                                                   const float* __restrict__ b_head,
                                                   float* __restrict__ out,
                                                   int* __restrict__ tbtot) {
    __shared__ int csh[4][CHN];
    const int t = blockIdx.x, b = blockIdx.y;
    const int tid = threadIdx.x;
    const int sub = tid >> 6, lane = tid & 63;
    const int q = lane >> 4, col = lane & 15;

    // slots for batch b: [b*512, b*512+512)
    int acc = 0;
    for (int s = sub; s < 512; s += 4) {
        unsigned v = P[((b * 512 + s) * TS + t) * 16 + col];
        acc += (int)((v >> (8 * q)) & 0xffu);
    }
    csh[sub][lane] = acc;
    __syncthreads();
    if (tid < CHN) {
        const int cnt = csh[0][lane] + csh[1][lane] + csh[2][lane] + csh[3][lane];
        const float s = (float)cnt * (1.f / (HH * WW));
        float a[NOUT];
#pragma unroll
        for (int o = 0; o < NOUT; ++o) a[o] = s * w_head[lane * NOUT + o];
        int tot = cnt;
#pragma unroll
        for (int off = 32; off > 0; off >>= 1) {
#pragma unroll
            for (int o = 0; o < NOUT; ++o) a[o] += __shfl_down(a[o], off);
            tot += __shfl_down(tot, off);
        }
        if (lane == 0) {
#pragma unroll
            for (int o = 0; o < NOUT; ++o)
                out[BB * NOUT + (t * BB + b) * NOUT + o] = a[o] + b_head[o];
            tbtot[t * BB + b] = tot;
        }
    }
}

// ---------------------------------------------------------------------------
// final: readout = mean_t(logits) ; sr = total spikes / denom
// ---------------------------------------------------------------------------
__global__ __launch_bounds__(256) void final_kernel(const int* __restrict__ tbtot,
                                                    float* __restrict__ out) {
    const int tid = threadIdx.x;
    const float* logits = out + BB * NOUT;
    if (tid < BB * NOUT) {
        const int b = tid / NOUT, o = tid - (tid / NOUT) * NOUT;
        float a = 0.f;
#pragma unroll
        for (int t = 0; t < TS; ++t) a += logits[(t * BB + b) * NOUT + o];
        out[tid] = a * (1.f / TS);
    }
    int s = 0;
    for (int i = tid; i < TS * BB; i += 256) s += tbtot[i];
#pragma unroll
    for (int off = 32; off > 0; off >>= 1) s += __shfl_down(s, off);
    __shared__ int red[4];
    if ((tid & 63) == 0) red[tid >> 6] = s;
    __syncthreads();
    if (tid == 0)
        out[BB * NOUT + TS * BB * NOUT] =
            (float)(red[0] + red[1] + red[2] + red[3]) *
            (1.f / ((float)TS * BB * HH * WW * CHN));
}

// ---------------------------------------------------------------------------
extern "C" void kernel_launch(void* const* d_in, const int* in_sizes, int n_in,
                              void* d_out, int out_size, void* d_ws, size_t ws_size,
                              hipStream_t stream) {
    (void)in_sizes; (void)n_in; (void)out_size; (void)ws_size;
    const float* x      = (const float*)d_in[0];
    const float* w_conv = (const float*)d_in[1];
    const float* b_conv = (const float*)d_in[2];
    const float* w_head = (const float*)d_in[3];
    const float* b_head = (const float*)d_in[4];
    float*    out   = (float*)d_out;
    unsigned* P     = (unsigned*)d_ws;
    int*      tbtot = (int*)d_ws + PDWORDS;

    // no memsets: every P slot and tbtot entry is written before it is read
    lif_main<<<dim3(2, HH / 2, BB), 256, 0, stream>>>(x, w_conv, b_conv, P);
    head_kernel<<<dim3(TS, BB), 256, 0, stream>>>(P, w_head, b_head, out, tbtot);
    final_kernel<<<1, 256, 0, stream>>>(tbtot, out);
}